// Round 11
// baseline (240.231 us; speedup 1.0000x reference)
//
#include <hip/hip_runtime.h>
#include <cstdint>
#include <cstddef>

#define NNODES 10000
#define NEDGES 320000
#define NPAD   10048
#define NBLK   157      // NPAD/64
#define CAP    128      // bucket capacity per node (Poisson(32) -> P(overflow) ~ 0)

#define BW0  128    // 128*256/256
#define BW1  256    // 256*256/256
#define BW2  64     // 256*64/256
#define BSC  1250   // 320000/256

typedef unsigned short ushort_t;
typedef short bf16x8 __attribute__((ext_vector_type(8)));
typedef float f32x4 __attribute__((ext_vector_type(4)));

__device__ __forceinline__ float lrelu(float x) { return x > 0.f ? x : 0.2f * x; }
__device__ __forceinline__ ushort_t f2b(float v) {
  unsigned b = __float_as_uint(v);
  b += 0x7fffu + ((b >> 16) & 1u);  // RNE
  return (ushort_t)(b >> 16);
}
__device__ __forceinline__ float blo(unsigned u) { return __uint_as_float(u << 16); }
__device__ __forceinline__ float bhi(unsigned u) { return __uint_as_float(u & 0xffff0000u); }
__device__ __forceinline__ bf16x8 cvt8(const float* p) {
  bf16x8 r;
#pragma unroll
  for (int i = 0; i < 8; ++i) r[i] = (short)f2b(p[i]);
  return r;
}

// ---------- prep: W0/W1/W2 -> WT bf16 transposes + bucket edge scatter ----------
// cursor must be zeroed beforehand (hipMemsetAsync).
__global__ __launch_bounds__(256) void prep_kernel(
    const float* __restrict__ W0, const float* __restrict__ W1, const float* __restrict__ W2,
    const int* __restrict__ ei,
    ushort_t* __restrict__ WT0, ushort_t* __restrict__ WT1, ushort_t* __restrict__ WT2,
    int* __restrict__ cursor, int* __restrict__ srcsPad) {
  int b = blockIdx.x;
  int tid = threadIdx.x;
  if (b < BW0) { int i = b * 256 + tid; int k = i >> 8, m = i & 255; WT0[m * 128 + k] = f2b(W0[i]); return; }
  b -= BW0;
  if (b < BW1) { int i = b * 256 + tid; int k = i >> 8, m = i & 255; WT1[m * 256 + k] = f2b(W1[i]); return; }
  b -= BW1;
  if (b < BW2) { int i = b * 256 + tid; int k = i >> 6, m = i & 63; WT2[m * 256 + k] = f2b(W2[i]); return; }
  b -= BW2;
  {
    int e = b * 256 + tid;
    int s = ei[e], d = ei[NEDGES + e];
    int slot = atomicAdd(&cursor[d], 1);
    srcsPad[d * CAP + slot] = s;  // capacity overflow statistically impossible
  }
}

// ---------- layer-0 GEMM: A = x (f32, converted in-register), B = WT0 ----------
// Writes h in HEAD-MAJOR layout: hbH[head][node][64] (1.25 MB per head slice).
__global__ __launch_bounds__(256) void gemm0_kernel(
    const float* __restrict__ x,       // [N,128] f32
    const ushort_t* __restrict__ WT,   // [256,128] bf16
    const float* __restrict__ atts, const float* __restrict__ attd,  // [256]
    ushort_t* __restrict__ hbH,        // [4][N][64] bf16 head-major
    float* __restrict__ a_s, float* __restrict__ a_d) {              // [N*4]
  const int K = 128;
  int tid = threadIdx.x, wave = tid >> 6, lane = tid & 63;
  int quad = lane >> 4, l16 = lane & 15;
  int n0 = blockIdx.x * 64, head = blockIdx.y, m0 = head * 64;
  int row = n0 + wave * 16 + l16;
  int rowc = row < NNODES ? row : NNODES - 1;  // clamp; garbage rows never stored
  f32x4 acc[4];
#pragma unroll
  for (int t = 0; t < 4; ++t) acc[t] = (f32x4){0.f, 0.f, 0.f, 0.f};
  const float* Ap = x + (size_t)rowc * K + quad * 8;
  const ushort_t* Wp = WT + (size_t)(m0 + l16) * K + quad * 8;
  for (int k0 = 0; k0 < K; k0 += 32) {
    bf16x8 af = cvt8(Ap + k0);
#pragma unroll
    for (int t = 0; t < 4; ++t) {
      bf16x8 bf = *(const bf16x8*)(Wp + (size_t)t * 16 * K + k0);
      acc[t] = __builtin_amdgcn_mfma_f32_16x16x32_bf16(af, bf, acc[t], 0, 0, 0);
    }
  }
#pragma unroll
  for (int reg = 0; reg < 4; ++reg) {
    int r = n0 + wave * 16 + quad * 4 + reg;
    float ps = 0.f, pd = 0.f;
#pragma unroll
    for (int t = 0; t < 4; ++t) {
      float v = acc[t][reg];
      int col = m0 + t * 16 + l16;
      ps = fmaf(v, atts[col], ps);
      pd = fmaf(v, attd[col], pd);
      if (r < NNODES) hbH[(size_t)(head * NNODES + r) * 64 + t * 16 + l16] = f2b(v);
    }
#pragma unroll
    for (int off = 8; off; off >>= 1) {
      ps += __shfl_xor(ps, off);
      pd += __shfl_xor(pd, off);
    }
    if (l16 == 0 && r < NNODES) {
      a_s[r * 4 + head] = ps;
      a_d[r * 4 + head] = pd;
    }
  }
}

// ---------- layers 1/2 GEMM: A bf16 from global, B = WT; head-major output ----------
template <int H>
__global__ __launch_bounds__(256) void gemm_att_kernel(
    const ushort_t* __restrict__ Ab,   // [N,256] bf16
    const ushort_t* __restrict__ WT,   // [H*64, 256] bf16
    const float* __restrict__ atts, const float* __restrict__ attd,
    ushort_t* __restrict__ hbH, float* __restrict__ a_s, float* __restrict__ a_d) {
  const int K = 256;
  int tid = threadIdx.x, wave = tid >> 6, lane = tid & 63;
  int quad = lane >> 4, l16 = lane & 15;
  int n0 = blockIdx.x * 64, head = blockIdx.y, m0 = head * 64;
  int row = n0 + wave * 16 + l16;
  int rowc = row < NNODES ? row : NNODES - 1;
  f32x4 acc[4];
#pragma unroll
  for (int t = 0; t < 4; ++t) acc[t] = (f32x4){0.f, 0.f, 0.f, 0.f};
  const ushort_t* Ap = Ab + (size_t)rowc * K + quad * 8;
  const ushort_t* Wp = WT + (size_t)(m0 + l16) * K + quad * 8;
  for (int k0 = 0; k0 < K; k0 += 32) {
    bf16x8 af = *(const bf16x8*)(Ap + k0);
#pragma unroll
    for (int t = 0; t < 4; ++t) {
      bf16x8 bf = *(const bf16x8*)(Wp + (size_t)t * 16 * K + k0);
      acc[t] = __builtin_amdgcn_mfma_f32_16x16x32_bf16(af, bf, acc[t], 0, 0, 0);
    }
  }
#pragma unroll
  for (int reg = 0; reg < 4; ++reg) {
    int r = n0 + wave * 16 + quad * 4 + reg;
    float ps = 0.f, pd = 0.f;
#pragma unroll
    for (int t = 0; t < 4; ++t) {
      float v = acc[t][reg];
      int col = m0 + t * 16 + l16;
      ps = fmaf(v, atts[col], ps);
      pd = fmaf(v, attd[col], pd);
      if (r < NNODES) hbH[(size_t)(head * NNODES + r) * 64 + t * 16 + l16] = f2b(v);
    }
#pragma unroll
    for (int off = 8; off; off >>= 1) {
      ps += __shfl_xor(ps, off);
      pd += __shfl_xor(pd, off);
    }
    if (l16 == 0 && r < NNODES) {
      a_s[r * H + head] = ps;
      a_d[r * H + head] = pd;
    }
  }
}

// ---------- gather cores (row stride now 128 B for ALL layers) ----------
__device__ __forceinline__ void gather8_full(const char* base, const float* alds,
                                             const int* olds, int esub, float acc[8]) {
#pragma unroll
  for (int it = 0; it < 8; ++it) {
    int e = it * 8 + esub;
    float a = alds[e];
    int o = olds[e];
    uint4 q = *(const uint4*)(base + o);
    acc[0] = fmaf(a, blo(q.x), acc[0]); acc[1] = fmaf(a, bhi(q.x), acc[1]);
    acc[2] = fmaf(a, blo(q.y), acc[2]); acc[3] = fmaf(a, bhi(q.y), acc[3]);
    acc[4] = fmaf(a, blo(q.z), acc[4]); acc[5] = fmaf(a, bhi(q.z), acc[5]);
    acc[6] = fmaf(a, blo(q.w), acc[6]); acc[7] = fmaf(a, bhi(q.w), acc[7]);
  }
}

__device__ __forceinline__ void gather8(const char* base, const float* alds, const int* olds,
                                        int cnt, int esub, float acc[8]) {
  int iters = (cnt + 7) >> 3;
  for (int it = 0; it < iters; ++it) {
    int e = it * 8 + esub;
    float a = alds[e];
    int o = olds[e];
    uint4 q = *(const uint4*)(base + o);
    acc[0] = fmaf(a, blo(q.x), acc[0]); acc[1] = fmaf(a, bhi(q.x), acc[1]);
    acc[2] = fmaf(a, blo(q.y), acc[2]); acc[3] = fmaf(a, bhi(q.y), acc[3]);
    acc[4] = fmaf(a, blo(q.z), acc[4]); acc[5] = fmaf(a, bhi(q.z), acc[5]);
    acc[6] = fmaf(a, blo(q.w), acc[6]); acc[7] = fmaf(a, bhi(q.w), acc[7]);
  }
}

// ---------- aggregation layers 0/1 (H=4): XCD-swizzled, one head per block ----------
// blockIdx.x = gg*8 + sub*4 + head; under round-robin block->XCD dispatch, each
// XCD sees only head = (xcd%4): its 1.25 MB head slice becomes L2-resident.
__global__ __launch_bounds__(256) void aggregate_kernel(
    const ushort_t* __restrict__ hbH, const float* __restrict__ a_s,
    const float* __restrict__ a_d,
    const int* __restrict__ cursor, const int* __restrict__ srcsPad,
    const float* __restrict__ bias, const float* __restrict__ gam, const float* __restrict__ bet,
    const float* __restrict__ rmean, const float* __restrict__ rvar,
    ushort_t* __restrict__ xb16) {
  __shared__ float s_alpha[4][64];
  __shared__ int s_off[4][64];
  int g = blockIdx.x;
  int xx = g & 7;
  int head = xx & 3;
  int group = (g >> 3) * 2 + (xx >> 2);   // [0, 2500)
  int wave = threadIdx.x >> 6;
  int n = group * 4 + wave;
  int lane = threadIdx.x & 63;
  int esub = lane >> 3, csub = lane & 7;
  float* alds = s_alpha[wave];
  int* olds = s_off[wave];
  int degi = cursor[n];
  int dtot = degi + 1;  // + self loop
  float adn = a_d[n * 4 + head];
  const char* base = (const char*)hbH + (size_t)head * NNODES * 128 + csub * 16;
  float acc[8];
#pragma unroll
  for (int i = 0; i < 8; ++i) acc[i] = 0.f;

  if (dtot <= 64) {
    int s = (lane < degi) ? srcsPad[n * CAP + lane] : n;  // lane==degi -> self; > -> alpha 0
    float l = (lane < dtot) ? lrelu(a_s[s * 4 + head] + adn) : -1e30f;
    float mx = l;
#pragma unroll
    for (int off = 32; off; off >>= 1) mx = fmaxf(mx, __shfl_xor(mx, off));
    float e = (lane < dtot) ? __expf(l - mx) : 0.f;
    float sum = e;
#pragma unroll
    for (int off = 32; off; off >>= 1) sum += __shfl_xor(sum, off);
    alds[lane] = e / (sum + 1e-16f);
    olds[lane] = s * 128;
    gather8_full(base, alds, olds, esub, acc);
  } else {
    float mx = -1e30f;
    for (int j = lane; j < dtot; j += 64) {
      int s = (j < degi) ? srcsPad[n * CAP + j] : n;
      mx = fmaxf(mx, lrelu(a_s[s * 4 + head] + adn));
    }
#pragma unroll
    for (int off = 32; off; off >>= 1) mx = fmaxf(mx, __shfl_xor(mx, off));
    float sum = 0.f;
    for (int j = lane; j < dtot; j += 64) {
      int s = (j < degi) ? srcsPad[n * CAP + j] : n;
      sum += __expf(lrelu(a_s[s * 4 + head] + adn) - mx);
    }
#pragma unroll
    for (int off = 32; off; off >>= 1) sum += __shfl_xor(sum, off);
    float inv = 1.0f / (sum + 1e-16f);
    for (int j0 = 0; j0 < dtot; j0 += 64) {
      int cnt = min(64, dtot - j0);
      int j = j0 + lane;
      int s = (j < degi) ? srcsPad[n * CAP + j] : n;
      alds[lane] = (lane < cnt) ? __expf(lrelu(a_s[s * 4 + head] + adn) - mx) * inv : 0.f;
      olds[lane] = s * 128;
      gather8(base, alds, olds, cnt, esub, acc);
    }
  }

#pragma unroll
  for (int i = 0; i < 8; ++i) {
    acc[i] += __shfl_xor(acc[i], 8);
    acc[i] += __shfl_xor(acc[i], 16);
    acc[i] += __shfl_xor(acc[i], 32);
  }
  if (esub == 0) {
    int col0 = head * 64 + csub * 8;
    float4 bi0 = *(const float4*)&bias[col0],  bi1 = *(const float4*)&bias[col0 + 4];
    float4 gm0 = *(const float4*)&gam[col0],   gm1 = *(const float4*)&gam[col0 + 4];
    float4 bt0 = *(const float4*)&bet[col0],   bt1 = *(const float4*)&bet[col0 + 4];
    float4 rm0 = *(const float4*)&rmean[col0], rm1 = *(const float4*)&rmean[col0 + 4];
    float4 rv0 = *(const float4*)&rvar[col0],  rv1 = *(const float4*)&rvar[col0 + 4];
    float bi[8] = {bi0.x, bi0.y, bi0.z, bi0.w, bi1.x, bi1.y, bi1.z, bi1.w};
    float gm[8] = {gm0.x, gm0.y, gm0.z, gm0.w, gm1.x, gm1.y, gm1.z, gm1.w};
    float bt[8] = {bt0.x, bt0.y, bt0.z, bt0.w, bt1.x, bt1.y, bt1.z, bt1.w};
    float rm[8] = {rm0.x, rm0.y, rm0.z, rm0.w, rm1.x, rm1.y, rm1.z, rm1.w};
    float rv[8] = {rv0.x, rv0.y, rv0.z, rv0.w, rv1.x, rv1.y, rv1.z, rv1.w};
    unsigned pk[4];
#pragma unroll
    for (int i = 0; i < 4; ++i) {
      float v0 = acc[2 * i] + bi[2 * i], v1 = acc[2 * i + 1] + bi[2 * i + 1];
      v0 = v0 > 0.f ? v0 : (__expf(v0) - 1.f);
      v1 = v1 > 0.f ? v1 : (__expf(v1) - 1.f);
      v0 = fmaf(gm[2 * i] * (v0 - rm[2 * i]), rsqrtf(rv[2 * i] + 1e-5f), bt[2 * i]);
      v1 = fmaf(gm[2 * i + 1] * (v1 - rm[2 * i + 1]), rsqrtf(rv[2 * i + 1] + 1e-5f), bt[2 * i + 1]);
      pk[i] = (unsigned)f2b(v0) | ((unsigned)f2b(v1) << 16);
    }
    *(uint4*)((char*)xb16 + (size_t)n * 512 + col0 * 2) = make_uint4(pk[0], pk[1], pk[2], pk[3]);
  }
}

// ---------- aggregation layer 2 (H=1) + bias + log_softmax ----------
__global__ __launch_bounds__(256) void aggregate2_kernel(
    const ushort_t* __restrict__ hb16,  // [N,64] bf16
    const float* __restrict__ a_s, const float* __restrict__ a_d,
    const int* __restrict__ cursor, const int* __restrict__ srcsPad,
    const float* __restrict__ bias, float* __restrict__ out) {
  __shared__ float s_alpha[4][64];
  __shared__ int s_off[4][64];
  int wave = threadIdx.x >> 6;
  int n = blockIdx.x * 4 + wave;
  int lane = threadIdx.x & 63;
  int esub = lane >> 3, csub = lane & 7;
  if (n >= NNODES) return;
  float* alds = s_alpha[wave];
  int* olds = s_off[wave];
  int degi = cursor[n];
  int dtot = degi + 1;
  float adn = a_d[n];
  const char* base = (const char*)hb16 + csub * 16;
  float acc[8];
#pragma unroll
  for (int i = 0; i < 8; ++i) acc[i] = 0.f;

  if (dtot <= 64) {
    int s = (lane < degi) ? srcsPad[n * CAP + lane] : n;
    float l = (lane < dtot) ? lrelu(a_s[s] + adn) : -1e30f;
    float mx = l;
#pragma unroll
    for (int off = 32; off; off >>= 1) mx = fmaxf(mx, __shfl_xor(mx, off));
    float e = (lane < dtot) ? __expf(l - mx) : 0.f;
    float sum = e;
#pragma unroll
    for (int off = 32; off; off >>= 1) sum += __shfl_xor(sum, off);
    alds[lane] = e / (sum + 1e-16f);
    olds[lane] = s * 128;
    gather8_full(base, alds, olds, esub, acc);
  } else {
    float mx = -1e30f;
    for (int j = lane; j < dtot; j += 64) {
      int s = (j < degi) ? srcsPad[n * CAP + j] : n;
      mx = fmaxf(mx, lrelu(a_s[s] + adn));
    }
#pragma unroll
    for (int off = 32; off; off >>= 1) mx = fmaxf(mx, __shfl_xor(mx, off));
    float sum = 0.f;
    for (int j = lane; j < dtot; j += 64) {
      int s = (j < degi) ? srcsPad[n * CAP + j] : n;
      sum += __expf(lrelu(a_s[s] + adn) - mx);
    }
#pragma unroll
    for (int off = 32; off; off >>= 1) sum += __shfl_xor(sum, off);
    float inv = 1.0f / (sum + 1e-16f);
    for (int j0 = 0; j0 < dtot; j0 += 64) {
      int cnt = min(64, dtot - j0);
      int j = j0 + lane;
      int s = (j < degi) ? srcsPad[n * CAP + j] : n;
      alds[lane] = (lane < cnt) ? __expf(lrelu(a_s[s] + adn) - mx) * inv : 0.f;
      olds[lane] = s * 128;
      gather8(base, alds, olds, cnt, esub, acc);
    }
  }

#pragma unroll
  for (int i = 0; i < 8; ++i) {
    acc[i] += __shfl_xor(acc[i], 8);
    acc[i] += __shfl_xor(acc[i], 16);
    acc[i] += __shfl_xor(acc[i], 32);
  }
  int col0 = csub * 8;
  float4 bi0 = *(const float4*)&bias[col0], bi1 = *(const float4*)&bias[col0 + 4];
  float v[8] = {acc[0] + bi0.x, acc[1] + bi0.y, acc[2] + bi0.z, acc[3] + bi0.w,
                acc[4] + bi1.x, acc[5] + bi1.y, acc[6] + bi1.z, acc[7] + bi1.w};
  float mx = v[0];
#pragma unroll
  for (int i = 1; i < 8; ++i) mx = fmaxf(mx, v[i]);
#pragma unroll
  for (int off = 4; off; off >>= 1) mx = fmaxf(mx, __shfl_xor(mx, off));
  float ex = 0.f;
#pragma unroll
  for (int i = 0; i < 8; ++i) ex += __expf(v[i] - mx);
#pragma unroll
  for (int off = 4; off; off >>= 1) ex += __shfl_xor(ex, off);
  float lse = mx + logf(ex);
  if (esub == 0) {
    float4 o0 = make_float4(v[0] - lse, v[1] - lse, v[2] - lse, v[3] - lse);
    float4 o1 = make_float4(v[4] - lse, v[5] - lse, v[6] - lse, v[7] - lse);
    *(float4*)&out[(size_t)n * 64 + col0] = o0;
    *(float4*)&out[(size_t)n * 64 + col0 + 4] = o1;
  }
}

// ---------- host ----------
extern "C" void kernel_launch(void* const* d_in, const int* in_sizes, int n_in,
                              void* d_out, int out_size, void* d_ws, size_t ws_size,
                              hipStream_t stream) {
  const float* x = (const float*)d_in[0];
  const int* ei = (const int*)d_in[1];
  const float* W0 = (const float*)d_in[2];
  const float* as0 = (const float*)d_in[3];
  const float* ad0 = (const float*)d_in[4];
  const float* b0 = (const float*)d_in[5];
  const float* g0p = (const float*)d_in[6];
  const float* be0 = (const float*)d_in[7];
  const float* m0p = (const float*)d_in[8];
  const float* v0p = (const float*)d_in[9];
  const float* W1 = (const float*)d_in[10];
  const float* as1 = (const float*)d_in[11];
  const float* ad1 = (const float*)d_in[12];
  const float* b1 = (const float*)d_in[13];
  const float* g1p = (const float*)d_in[14];
  const float* be1 = (const float*)d_in[15];
  const float* m1p = (const float*)d_in[16];
  const float* v1p = (const float*)d_in[17];
  const float* W2 = (const float*)d_in[18];
  const float* as2 = (const float*)d_in[19];
  const float* ad2 = (const float*)d_in[20];
  const float* b2 = (const float*)d_in[21];
  float* out = (float*)d_out;

  char* w = (char*)d_ws;
  auto alloc = [&](size_t bytes) {
    void* r = (void*)w;
    w += (bytes + 255) & ~(size_t)255;
    return r;
  };
  ushort_t* hb = (ushort_t*)alloc((size_t)NNODES * 256 * 2);   // head-major h (reused)
  ushort_t* xb = (ushort_t*)alloc((size_t)NNODES * 256 * 2);   // aggregate output (reused)
  ushort_t* WT0 = (ushort_t*)alloc((size_t)256 * 128 * 2);
  ushort_t* WT1 = (ushort_t*)alloc((size_t)256 * 256 * 2);
  ushort_t* WT2 = (ushort_t*)alloc((size_t)64 * 256 * 2);
  float* a_s = (float*)alloc((size_t)NNODES * 4 * 4);
  float* a_d = (float*)alloc((size_t)NNODES * 4 * 4);
  int* cursor = (int*)alloc((size_t)NNODES * 4);
  int* srcsPad = (int*)alloc((size_t)NNODES * CAP * 4);

  // 1. zero bucket cursors
  hipMemsetAsync(cursor, 0, (size_t)NNODES * 4, stream);
  // 2. prep: W transposes + bucket scatter
  prep_kernel<<<BW0 + BW1 + BW2 + BSC, 256, 0, stream>>>(
      W0, W1, W2, ei, WT0, WT1, WT2, cursor, srcsPad);
  // 3. layer-0 GEMM (inline f32->bf16 A conversion) + att -> head-major hb
  gemm0_kernel<<<dim3(NBLK, 4), 256, 0, stream>>>(x, WT0, as0, ad0, hb, a_s, a_d);
  // 4. layer-0 aggregate (XCD-swizzled heads)
  aggregate_kernel<<<NNODES, 256, 0, stream>>>(hb, a_s, a_d, cursor, srcsPad,
                                               b0, g0p, be0, m0p, v0p, xb);
  // 5-6. layer 1
  gemm_att_kernel<4><<<dim3(NBLK, 4), 256, 0, stream>>>(xb, WT1, as1, ad1, hb, a_s, a_d);
  aggregate_kernel<<<NNODES, 256, 0, stream>>>(hb, a_s, a_d, cursor, srcsPad,
                                               b1, g1p, be1, m1p, v1p, xb);
  // 7-8. layer 2
  gemm_att_kernel<1><<<dim3(NBLK, 1), 256, 0, stream>>>(xb, WT2, as2, ad2, hb, a_s, a_d);
  aggregate2_kernel<<<(NNODES + 3) / 4, 256, 0, stream>>>(hb, a_s, a_d, cursor, srcsPad,
                                                          b2, out);
}

// Round 12
// 231.187 us; speedup vs baseline: 1.0391x; 1.0391x over previous
//
#include <hip/hip_runtime.h>
#include <cstdint>
#include <cstddef>

#define NNODES 10000
#define NEDGES 320000
#define NPAD   10048
#define NBLK   157      // NPAD/64
#define CAP    128      // bucket capacity per node (Poisson(32) -> P(overflow) ~ 0)

#define BW0  128    // 128*256/256
#define BW1  256    // 256*256/256
#define BW2  64     // 256*64/256
#define BSC  1250   // 320000/256

typedef unsigned short ushort_t;
typedef short bf16x8 __attribute__((ext_vector_type(8)));
typedef float f32x4 __attribute__((ext_vector_type(4)));

__device__ __forceinline__ float lrelu(float x) { return x > 0.f ? x : 0.2f * x; }
__device__ __forceinline__ ushort_t f2b(float v) {
  unsigned b = __float_as_uint(v);
  b += 0x7fffu + ((b >> 16) & 1u);  // RNE
  return (ushort_t)(b >> 16);
}
__device__ __forceinline__ float blo(unsigned u) { return __uint_as_float(u << 16); }
__device__ __forceinline__ float bhi(unsigned u) { return __uint_as_float(u & 0xffff0000u); }
__device__ __forceinline__ bf16x8 cvt8(const float* p) {
  bf16x8 r;
#pragma unroll
  for (int i = 0; i < 8; ++i) r[i] = (short)f2b(p[i]);
  return r;
}

// ---------- prep: W0/W1/W2 -> WT bf16 transposes only ----------
__global__ __launch_bounds__(256) void prep_kernel(
    const float* __restrict__ W0, const float* __restrict__ W1, const float* __restrict__ W2,
    ushort_t* __restrict__ WT0, ushort_t* __restrict__ WT1, ushort_t* __restrict__ WT2) {
  int b = blockIdx.x;
  int tid = threadIdx.x;
  if (b < BW0) { int i = b * 256 + tid; int k = i >> 8, m = i & 255; WT0[m * 128 + k] = f2b(W0[i]); return; }
  b -= BW0;
  if (b < BW1) { int i = b * 256 + tid; int k = i >> 8, m = i & 255; WT1[m * 256 + k] = f2b(W1[i]); return; }
  b -= BW1;
  { int i = b * 256 + tid; int k = i >> 6, m = i & 63; WT2[m * 256 + k] = f2b(W2[i]); }
}

// ---------- MFMA GEMM tile, layer 0 (A = f32 x, converted in-register) ----------
__device__ __forceinline__ void gemm0_tile(
    const float* __restrict__ x, const ushort_t* __restrict__ WT,
    const float* __restrict__ atts, const float* __restrict__ attd,
    ushort_t* __restrict__ hb, float* __restrict__ a_s, float* __restrict__ a_d,
    int n0, int head) {
  const int K = 128, M = 256;
  int tid = threadIdx.x, wave = tid >> 6, lane = tid & 63;
  int quad = lane >> 4, l16 = lane & 15;
  int m0 = head * 64;
  int row = n0 + wave * 16 + l16;
  int rowc = row < NNODES ? row : NNODES - 1;  // clamp; garbage rows never stored
  f32x4 acc[4];
#pragma unroll
  for (int t = 0; t < 4; ++t) acc[t] = (f32x4){0.f, 0.f, 0.f, 0.f};
  const float* Ap = x + (size_t)rowc * K + quad * 8;
  const ushort_t* Wp = WT + (size_t)(m0 + l16) * K + quad * 8;
  for (int k0 = 0; k0 < K; k0 += 32) {
    bf16x8 af = cvt8(Ap + k0);
#pragma unroll
    for (int t = 0; t < 4; ++t) {
      bf16x8 bf = *(const bf16x8*)(Wp + (size_t)t * 16 * K + k0);
      acc[t] = __builtin_amdgcn_mfma_f32_16x16x32_bf16(af, bf, acc[t], 0, 0, 0);
    }
  }
#pragma unroll
  for (int reg = 0; reg < 4; ++reg) {
    int r = n0 + wave * 16 + quad * 4 + reg;
    float ps = 0.f, pd = 0.f;
#pragma unroll
    for (int t = 0; t < 4; ++t) {
      float v = acc[t][reg];
      int col = m0 + t * 16 + l16;
      ps = fmaf(v, atts[col], ps);
      pd = fmaf(v, attd[col], pd);
      if (r < NNODES) hb[(size_t)r * M + col] = f2b(v);
    }
#pragma unroll
    for (int off = 8; off; off >>= 1) {
      ps += __shfl_xor(ps, off);
      pd += __shfl_xor(pd, off);
    }
    if (l16 == 0 && r < NNODES) {
      a_s[r * 4 + head] = ps;
      a_d[r * 4 + head] = pd;
    }
  }
}

// layer-0 GEMM fused with bucket edge scatter (independent work, one dispatch;
// scatter's atomic-latency waves fill CUs the 628 gemm blocks leave idle)
__global__ __launch_bounds__(256) void gemm0_scatter_kernel(
    const float* __restrict__ x, const ushort_t* __restrict__ WT,
    const float* __restrict__ atts, const float* __restrict__ attd,
    ushort_t* __restrict__ hb, float* __restrict__ a_s, float* __restrict__ a_d,
    const int* __restrict__ ei, int* __restrict__ cursor, int* __restrict__ srcsPad) {
  int b = blockIdx.x;
  if (b < NBLK * 4) {
    gemm0_tile(x, WT, atts, attd, hb, a_s, a_d, (b % NBLK) * 64, b / NBLK);
  } else {
    int e = (b - NBLK * 4) * 256 + threadIdx.x;
    int s = ei[e], d = ei[NEDGES + e];
    int slot = atomicAdd(&cursor[d], 1);
    srcsPad[d * CAP + slot] = s;  // capacity overflow statistically impossible
  }
}

// ---------- layers 1/2 GEMM: A bf16 from global, B = WT ----------
template <int H>
__global__ __launch_bounds__(256) void gemm_att_kernel(
    const ushort_t* __restrict__ Ab,   // [N,256] bf16
    const ushort_t* __restrict__ WT,   // [H*64, 256] bf16
    const float* __restrict__ atts, const float* __restrict__ attd,
    ushort_t* __restrict__ hb, float* __restrict__ a_s, float* __restrict__ a_d) {
  const int K = 256, M = H * 64;
  int tid = threadIdx.x, wave = tid >> 6, lane = tid & 63;
  int quad = lane >> 4, l16 = lane & 15;
  int n0 = blockIdx.x * 64, head = blockIdx.y, m0 = head * 64;
  int row = n0 + wave * 16 + l16;
  int rowc = row < NNODES ? row : NNODES - 1;
  f32x4 acc[4];
#pragma unroll
  for (int t = 0; t < 4; ++t) acc[t] = (f32x4){0.f, 0.f, 0.f, 0.f};
  const ushort_t* Ap = Ab + (size_t)rowc * K + quad * 8;
  const ushort_t* Wp = WT + (size_t)(m0 + l16) * K + quad * 8;
  for (int k0 = 0; k0 < K; k0 += 32) {
    bf16x8 af = *(const bf16x8*)(Ap + k0);
#pragma unroll
    for (int t = 0; t < 4; ++t) {
      bf16x8 bf = *(const bf16x8*)(Wp + (size_t)t * 16 * K + k0);
      acc[t] = __builtin_amdgcn_mfma_f32_16x16x32_bf16(af, bf, acc[t], 0, 0, 0);
    }
  }
#pragma unroll
  for (int reg = 0; reg < 4; ++reg) {
    int r = n0 + wave * 16 + quad * 4 + reg;
    float ps = 0.f, pd = 0.f;
#pragma unroll
    for (int t = 0; t < 4; ++t) {
      float v = acc[t][reg];
      int col = m0 + t * 16 + l16;
      ps = fmaf(v, atts[col], ps);
      pd = fmaf(v, attd[col], pd);
      if (r < NNODES) hb[(size_t)r * M + col] = f2b(v);
    }
#pragma unroll
    for (int off = 8; off; off >>= 1) {
      ps += __shfl_xor(ps, off);
      pd += __shfl_xor(pd, off);
    }
    if (l16 == 0 && r < NNODES) {
      a_s[r * H + head] = ps;
      a_d[r * H + head] = pd;
    }
  }
}

// ---------- gather cores ----------
__device__ __forceinline__ void gather8_full(const char* base, const float* alds,
                                             const int* olds, int esub, float acc[8]) {
#pragma unroll
  for (int it = 0; it < 8; ++it) {
    int e = it * 8 + esub;
    float a = alds[e];
    int o = olds[e];
    uint4 q = *(const uint4*)(base + o);
    acc[0] = fmaf(a, blo(q.x), acc[0]); acc[1] = fmaf(a, bhi(q.x), acc[1]);
    acc[2] = fmaf(a, blo(q.y), acc[2]); acc[3] = fmaf(a, bhi(q.y), acc[3]);
    acc[4] = fmaf(a, blo(q.z), acc[4]); acc[5] = fmaf(a, bhi(q.z), acc[5]);
    acc[6] = fmaf(a, blo(q.w), acc[6]); acc[7] = fmaf(a, bhi(q.w), acc[7]);
  }
}

__device__ __forceinline__ void gather8(const char* base, const float* alds, const int* olds,
                                        int cnt, int esub, float acc[8]) {
  int iters = (cnt + 7) >> 3;
  for (int it = 0; it < iters; ++it) {
    int e = it * 8 + esub;
    float a = alds[e];
    int o = olds[e];
    uint4 q = *(const uint4*)(base + o);
    acc[0] = fmaf(a, blo(q.x), acc[0]); acc[1] = fmaf(a, bhi(q.x), acc[1]);
    acc[2] = fmaf(a, blo(q.y), acc[2]); acc[3] = fmaf(a, bhi(q.y), acc[3]);
    acc[4] = fmaf(a, blo(q.z), acc[4]); acc[5] = fmaf(a, bhi(q.z), acc[5]);
    acc[6] = fmaf(a, blo(q.w), acc[6]); acc[7] = fmaf(a, bhi(q.w), acc[7]);
  }
}

// ---------- aggregation layers 0/1 (H=4): softmax + gather + bias+ELU+BN ----------
__global__ __launch_bounds__(256) void aggregate_kernel(
    const ushort_t* __restrict__ hb16, const float* __restrict__ a_s,
    const float* __restrict__ a_d,
    const int* __restrict__ cursor, const int* __restrict__ srcsPad,
    const float* __restrict__ bias, const float* __restrict__ gam, const float* __restrict__ bet,
    const float* __restrict__ rmean, const float* __restrict__ rvar,
    ushort_t* __restrict__ xb16) {
  __shared__ float s_alpha[4][64];
  __shared__ int s_off[4][64];
  int n = blockIdx.x;
  int hh = threadIdx.x >> 6;  // wave = head
  int lane = threadIdx.x & 63;
  int esub = lane >> 3, csub = lane & 7;
  float* alds = s_alpha[hh];
  int* olds = s_off[hh];
  int degi = cursor[n];
  int dtot = degi + 1;  // + self loop
  float adn = a_d[n * 4 + hh];
  const char* base = (const char*)hb16 + hh * 128 + csub * 16;
  float acc[8];
#pragma unroll
  for (int i = 0; i < 8; ++i) acc[i] = 0.f;

  if (dtot <= 64) {
    int s = (lane < degi) ? srcsPad[n * CAP + lane] : n;  // lane==degi -> self; > -> alpha 0
    float l = (lane < dtot) ? lrelu(a_s[s * 4 + hh] + adn) : -1e30f;
    float mx = l;
#pragma unroll
    for (int off = 32; off; off >>= 1) mx = fmaxf(mx, __shfl_xor(mx, off));
    float e = (lane < dtot) ? __expf(l - mx) : 0.f;
    float sum = e;
#pragma unroll
    for (int off = 32; off; off >>= 1) sum += __shfl_xor(sum, off);
    alds[lane] = e / (sum + 1e-16f);
    olds[lane] = s * 512;
    gather8_full(base, alds, olds, esub, acc);
  } else {
    float mx = -1e30f;
    for (int j = lane; j < dtot; j += 64) {
      int s = (j < degi) ? srcsPad[n * CAP + j] : n;
      mx = fmaxf(mx, lrelu(a_s[s * 4 + hh] + adn));
    }
#pragma unroll
    for (int off = 32; off; off >>= 1) mx = fmaxf(mx, __shfl_xor(mx, off));
    float sum = 0.f;
    for (int j = lane; j < dtot; j += 64) {
      int s = (j < degi) ? srcsPad[n * CAP + j] : n;
      sum += __expf(lrelu(a_s[s * 4 + hh] + adn) - mx);
    }
#pragma unroll
    for (int off = 32; off; off >>= 1) sum += __shfl_xor(sum, off);
    float inv = 1.0f / (sum + 1e-16f);
    for (int j0 = 0; j0 < dtot; j0 += 64) {
      int cnt = min(64, dtot - j0);
      int j = j0 + lane;
      int s = (j < degi) ? srcsPad[n * CAP + j] : n;
      alds[lane] = (lane < cnt) ? __expf(lrelu(a_s[s * 4 + hh] + adn) - mx) * inv : 0.f;
      olds[lane] = s * 512;
      gather8(base, alds, olds, cnt, esub, acc);
    }
  }

#pragma unroll
  for (int i = 0; i < 8; ++i) {
    acc[i] += __shfl_xor(acc[i], 8);
    acc[i] += __shfl_xor(acc[i], 16);
    acc[i] += __shfl_xor(acc[i], 32);
  }
  if (esub == 0) {
    int col0 = hh * 64 + csub * 8;
    float4 bi0 = *(const float4*)&bias[col0],  bi1 = *(const float4*)&bias[col0 + 4];
    float4 gm0 = *(const float4*)&gam[col0],   gm1 = *(const float4*)&gam[col0 + 4];
    float4 bt0 = *(const float4*)&bet[col0],   bt1 = *(const float4*)&bet[col0 + 4];
    float4 rm0 = *(const float4*)&rmean[col0], rm1 = *(const float4*)&rmean[col0 + 4];
    float4 rv0 = *(const float4*)&rvar[col0],  rv1 = *(const float4*)&rvar[col0 + 4];
    float bi[8] = {bi0.x, bi0.y, bi0.z, bi0.w, bi1.x, bi1.y, bi1.z, bi1.w};
    float gm[8] = {gm0.x, gm0.y, gm0.z, gm0.w, gm1.x, gm1.y, gm1.z, gm1.w};
    float bt[8] = {bt0.x, bt0.y, bt0.z, bt0.w, bt1.x, bt1.y, bt1.z, bt1.w};
    float rm[8] = {rm0.x, rm0.y, rm0.z, rm0.w, rm1.x, rm1.y, rm1.z, rm1.w};
    float rv[8] = {rv0.x, rv0.y, rv0.z, rv0.w, rv1.x, rv1.y, rv1.z, rv1.w};
    unsigned pk[4];
#pragma unroll
    for (int i = 0; i < 4; ++i) {
      float v0 = acc[2 * i] + bi[2 * i], v1 = acc[2 * i + 1] + bi[2 * i + 1];
      v0 = v0 > 0.f ? v0 : (__expf(v0) - 1.f);
      v1 = v1 > 0.f ? v1 : (__expf(v1) - 1.f);
      v0 = fmaf(gm[2 * i] * (v0 - rm[2 * i]), rsqrtf(rv[2 * i] + 1e-5f), bt[2 * i]);
      v1 = fmaf(gm[2 * i + 1] * (v1 - rm[2 * i + 1]), rsqrtf(rv[2 * i + 1] + 1e-5f), bt[2 * i + 1]);
      pk[i] = (unsigned)f2b(v0) | ((unsigned)f2b(v1) << 16);
    }
    *(uint4*)((char*)xb16 + (size_t)n * 512 + col0 * 2) = make_uint4(pk[0], pk[1], pk[2], pk[3]);
  }
}

// ---------- aggregation layer 2 (H=1) + bias + log_softmax ----------
__global__ __launch_bounds__(256) void aggregate2_kernel(
    const ushort_t* __restrict__ hb16, const float* __restrict__ a_s,
    const float* __restrict__ a_d,
    const int* __restrict__ cursor, const int* __restrict__ srcsPad,
    const float* __restrict__ bias, float* __restrict__ out) {
  __shared__ float s_alpha[4][64];
  __shared__ int s_off[4][64];
  int wave = threadIdx.x >> 6;
  int n = blockIdx.x * 4 + wave;
  int lane = threadIdx.x & 63;
  int esub = lane >> 3, csub = lane & 7;
  if (n >= NNODES) return;
  float* alds = s_alpha[wave];
  int* olds = s_off[wave];
  int degi = cursor[n];
  int dtot = degi + 1;
  float adn = a_d[n];
  const char* base = (const char*)hb16 + csub * 16;
  float acc[8];
#pragma unroll
  for (int i = 0; i < 8; ++i) acc[i] = 0.f;

  if (dtot <= 64) {
    int s = (lane < degi) ? srcsPad[n * CAP + lane] : n;
    float l = (lane < dtot) ? lrelu(a_s[s] + adn) : -1e30f;
    float mx = l;
#pragma unroll
    for (int off = 32; off; off >>= 1) mx = fmaxf(mx, __shfl_xor(mx, off));
    float e = (lane < dtot) ? __expf(l - mx) : 0.f;
    float sum = e;
#pragma unroll
    for (int off = 32; off; off >>= 1) sum += __shfl_xor(sum, off);
    alds[lane] = e / (sum + 1e-16f);
    olds[lane] = s * 128;
    gather8_full(base, alds, olds, esub, acc);
  } else {
    float mx = -1e30f;
    for (int j = lane; j < dtot; j += 64) {
      int s = (j < degi) ? srcsPad[n * CAP + j] : n;
      mx = fmaxf(mx, lrelu(a_s[s] + adn));
    }
#pragma unroll
    for (int off = 32; off; off >>= 1) mx = fmaxf(mx, __shfl_xor(mx, off));
    float sum = 0.f;
    for (int j = lane; j < dtot; j += 64) {
      int s = (j < degi) ? srcsPad[n * CAP + j] : n;
      sum += __expf(lrelu(a_s[s] + adn) - mx);
    }
#pragma unroll
    for (int off = 32; off; off >>= 1) sum += __shfl_xor(sum, off);
    float inv = 1.0f / (sum + 1e-16f);
    for (int j0 = 0; j0 < dtot; j0 += 64) {
      int cnt = min(64, dtot - j0);
      int j = j0 + lane;
      int s = (j < degi) ? srcsPad[n * CAP + j] : n;
      alds[lane] = (lane < cnt) ? __expf(lrelu(a_s[s] + adn) - mx) * inv : 0.f;
      olds[lane] = s * 128;
      gather8(base, alds, olds, cnt, esub, acc);
    }
  }

#pragma unroll
  for (int i = 0; i < 8; ++i) {
    acc[i] += __shfl_xor(acc[i], 8);
    acc[i] += __shfl_xor(acc[i], 16);
    acc[i] += __shfl_xor(acc[i], 32);
  }
  int col0 = csub * 8;
  float4 bi0 = *(const float4*)&bias[col0], bi1 = *(const float4*)&bias[col0 + 4];
  float v[8] = {acc[0] + bi0.x, acc[1] + bi0.y, acc[2] + bi0.z, acc[3] + bi0.w,
                acc[4] + bi1.x, acc[5] + bi1.y, acc[6] + bi1.z, acc[7] + bi1.w};
  float mx = v[0];
#pragma unroll
  for (int i = 1; i < 8; ++i) mx = fmaxf(mx, v[i]);
#pragma unroll
  for (int off = 4; off; off >>= 1) mx = fmaxf(mx, __shfl_xor(mx, off));
  float ex = 0.f;
#pragma unroll
  for (int i = 0; i < 8; ++i) ex += __expf(v[i] - mx);
#pragma unroll
  for (int off = 4; off; off >>= 1) ex += __shfl_xor(ex, off);
  float lse = mx + logf(ex);
  if (esub == 0) {
    float4 o0 = make_float4(v[0] - lse, v[1] - lse, v[2] - lse, v[3] - lse);
    float4 o1 = make_float4(v[4] - lse, v[5] - lse, v[6] - lse, v[7] - lse);
    *(float4*)&out[(size_t)n * 64 + col0] = o0;
    *(float4*)&out[(size_t)n * 64 + col0 + 4] = o1;
  }
}

// ---------- host ----------
extern "C" void kernel_launch(void* const* d_in, const int* in_sizes, int n_in,
                              void* d_out, int out_size, void* d_ws, size_t ws_size,
                              hipStream_t stream) {
  const float* x = (const float*)d_in[0];
  const int* ei = (const int*)d_in[1];
  const float* W0 = (const float*)d_in[2];
  const float* as0 = (const float*)d_in[3];
  const float* ad0 = (const float*)d_in[4];
  const float* b0 = (const float*)d_in[5];
  const float* g0p = (const float*)d_in[6];
  const float* be0 = (const float*)d_in[7];
  const float* m0p = (const float*)d_in[8];
  const float* v0p = (const float*)d_in[9];
  const float* W1 = (const float*)d_in[10];
  const float* as1 = (const float*)d_in[11];
  const float* ad1 = (const float*)d_in[12];
  const float* b1 = (const float*)d_in[13];
  const float* g1p = (const float*)d_in[14];
  const float* be1 = (const float*)d_in[15];
  const float* m1p = (const float*)d_in[16];
  const float* v1p = (const float*)d_in[17];
  const float* W2 = (const float*)d_in[18];
  const float* as2 = (const float*)d_in[19];
  const float* ad2 = (const float*)d_in[20];
  const float* b2 = (const float*)d_in[21];
  float* out = (float*)d_out;

  char* w = (char*)d_ws;
  auto alloc = [&](size_t bytes) {
    void* r = (void*)w;
    w += (bytes + 255) & ~(size_t)255;
    return r;
  };
  ushort_t* hb = (ushort_t*)alloc((size_t)NNODES * 256 * 2);   // per-layer h (reused)
  ushort_t* xb = (ushort_t*)alloc((size_t)NNODES * 256 * 2);   // aggregate output (reused)
  ushort_t* WT0 = (ushort_t*)alloc((size_t)256 * 128 * 2);
  ushort_t* WT1 = (ushort_t*)alloc((size_t)256 * 256 * 2);
  ushort_t* WT2 = (ushort_t*)alloc((size_t)64 * 256 * 2);
  float* a_s = (float*)alloc((size_t)NNODES * 4 * 4);
  float* a_d = (float*)alloc((size_t)NNODES * 4 * 4);
  int* cursor = (int*)alloc((size_t)NNODES * 4);
  int* srcsPad = (int*)alloc((size_t)NNODES * CAP * 4);

  // 1. zero bucket cursors
  hipMemsetAsync(cursor, 0, (size_t)NNODES * 4, stream);
  // 2. prep: W transposes only (~3 us)
  prep_kernel<<<BW0 + BW1 + BW2, 256, 0, stream>>>(W0, W1, W2, WT0, WT1, WT2);
  // 3. layer-0 GEMM + att, fused with bucket scatter (overlapping independent work)
  gemm0_scatter_kernel<<<NBLK * 4 + BSC, 256, 0, stream>>>(
      x, WT0, as0, ad0, hb, a_s, a_d, ei, cursor, srcsPad);
  // 4. layer-0 aggregate
  aggregate_kernel<<<NNODES, 256, 0, stream>>>(hb, a_s, a_d, cursor, srcsPad,
                                               b0, g0p, be0, m0p, v0p, xb);
  // 5-6. layer 1
  gemm_att_kernel<4><<<dim3(NBLK, 4), 256, 0, stream>>>(xb, WT1, as1, ad1, hb, a_s, a_d);
  aggregate_kernel<<<NNODES, 256, 0, stream>>>(hb, a_s, a_d, cursor, srcsPad,
                                               b1, g1p, be1, m1p, v1p, xb);
  // 7-8. layer 2
  gemm_att_kernel<1><<<dim3(NBLK, 1), 256, 0, stream>>>(xb, WT2, as2, ad2, hb, a_s, a_d);
  aggregate2_kernel<<<(NNODES + 3) / 4, 256, 0, stream>>>(hb, a_s, a_d, cursor, srcsPad,
                                                          b2, out);
}

// Round 13
// 226.130 us; speedup vs baseline: 1.0624x; 1.0224x over previous
//
#include <hip/hip_runtime.h>
#include <cstdint>
#include <cstddef>

#define NNODES 10000
#define NEDGES 320000
#define NPAD   10048
#define NBLK   157      // NPAD/64
#define CAP    128      // bucket capacity per node (Poisson(32) -> P(overflow) ~ 0)

#define BW0  128    // 128*256/256 (W0 transpose blocks, in prep)
#define BZ   40     // cursor-zero blocks, in prep
#define BW1  256    // 256*256/256 (W1 transpose blocks, in gemm0 dispatch)
#define BW2  64     // 256*64/256  (W2 transpose blocks, in gemm0 dispatch)
#define BSC  1250   // 320000/256  (scatter blocks, in gemm0 dispatch)

typedef unsigned short ushort_t;
typedef short bf16x8 __attribute__((ext_vector_type(8)));
typedef float f32x4 __attribute__((ext_vector_type(4)));

__device__ __forceinline__ float lrelu(float x) { return x > 0.f ? x : 0.2f * x; }
__device__ __forceinline__ ushort_t f2b(float v) {
  unsigned b = __float_as_uint(v);
  b += 0x7fffu + ((b >> 16) & 1u);  // RNE
  return (ushort_t)(b >> 16);
}
__device__ __forceinline__ float blo(unsigned u) { return __uint_as_float(u << 16); }
__device__ __forceinline__ float bhi(unsigned u) { return __uint_as_float(u & 0xffff0000u); }
__device__ __forceinline__ bf16x8 cvt8(const float* p) {
  bf16x8 r;
#pragma unroll
  for (int i = 0; i < 8; ++i) r[i] = (short)f2b(p[i]);
  return r;
}

// ---------- prep: W0 -> WT0 bf16 transpose + cursor zeroing ----------
// (cursor consumed by the scatter in the NEXT dispatch; WT0 by gemm0)
__global__ __launch_bounds__(256) void prep_kernel(
    const float* __restrict__ W0, ushort_t* __restrict__ WT0, int* __restrict__ cursor) {
  int b = blockIdx.x;
  int tid = threadIdx.x;
  if (b < BW0) {
    int i = b * 256 + tid; int k = i >> 8, m = i & 255;
    WT0[m * 128 + k] = f2b(W0[i]);
  } else {
    int i = (b - BW0) * 256 + tid;
    if (i < NNODES) cursor[i] = 0;
  }
}

// ---------- MFMA GEMM tile, layer 0 (A = f32 x, converted in-register) ----------
__device__ __forceinline__ void gemm0_tile(
    const float* __restrict__ x, const ushort_t* __restrict__ WT,
    const float* __restrict__ atts, const float* __restrict__ attd,
    ushort_t* __restrict__ hb, float* __restrict__ a_s, float* __restrict__ a_d,
    int n0, int head) {
  const int K = 128, M = 256;
  int tid = threadIdx.x, wave = tid >> 6, lane = tid & 63;
  int quad = lane >> 4, l16 = lane & 15;
  int m0 = head * 64;
  int row = n0 + wave * 16 + l16;
  int rowc = row < NNODES ? row : NNODES - 1;  // clamp; garbage rows never stored
  f32x4 acc[4];
#pragma unroll
  for (int t = 0; t < 4; ++t) acc[t] = (f32x4){0.f, 0.f, 0.f, 0.f};
  const float* Ap = x + (size_t)rowc * K + quad * 8;
  const ushort_t* Wp = WT + (size_t)(m0 + l16) * K + quad * 8;
  for (int k0 = 0; k0 < K; k0 += 32) {
    bf16x8 af = cvt8(Ap + k0);
#pragma unroll
    for (int t = 0; t < 4; ++t) {
      bf16x8 bf = *(const bf16x8*)(Wp + (size_t)t * 16 * K + k0);
      acc[t] = __builtin_amdgcn_mfma_f32_16x16x32_bf16(af, bf, acc[t], 0, 0, 0);
    }
  }
#pragma unroll
  for (int reg = 0; reg < 4; ++reg) {
    int r = n0 + wave * 16 + quad * 4 + reg;
    float ps = 0.f, pd = 0.f;
#pragma unroll
    for (int t = 0; t < 4; ++t) {
      float v = acc[t][reg];
      int col = m0 + t * 16 + l16;
      ps = fmaf(v, atts[col], ps);
      pd = fmaf(v, attd[col], pd);
      if (r < NNODES) hb[(size_t)r * M + col] = f2b(v);
    }
#pragma unroll
    for (int off = 8; off; off >>= 1) {
      ps += __shfl_xor(ps, off);
      pd += __shfl_xor(pd, off);
    }
    if (l16 == 0 && r < NNODES) {
      a_s[r * 4 + head] = ps;
      a_d[r * 4 + head] = pd;
    }
  }
}

// layer-0 GEMM fused with: bucket edge scatter + W1/W2 transposes.
// All independent of gemm0's output; WT1/WT2 consumed only by later dispatches.
__global__ __launch_bounds__(256) void gemm0_scatter_kernel(
    const float* __restrict__ x, const ushort_t* __restrict__ WT,
    const float* __restrict__ atts, const float* __restrict__ attd,
    ushort_t* __restrict__ hb, float* __restrict__ a_s, float* __restrict__ a_d,
    const int* __restrict__ ei, int* __restrict__ cursor, int* __restrict__ srcsPad,
    const float* __restrict__ W1, const float* __restrict__ W2,
    ushort_t* __restrict__ WT1, ushort_t* __restrict__ WT2) {
  int b = blockIdx.x;
  int tid = threadIdx.x;
  if (b < NBLK * 4) {
    gemm0_tile(x, WT, atts, attd, hb, a_s, a_d, (b % NBLK) * 64, b / NBLK);
    return;
  }
  b -= NBLK * 4;
  if (b < BSC) {
    int e = b * 256 + tid;
    int s = ei[e], d = ei[NEDGES + e];
    int slot = atomicAdd(&cursor[d], 1);
    srcsPad[d * CAP + slot] = s;  // capacity overflow statistically impossible
    return;
  }
  b -= BSC;
  if (b < BW1) {
    int i = b * 256 + tid; int k = i >> 8, m = i & 255;
    WT1[m * 256 + k] = f2b(W1[i]);
    return;
  }
  b -= BW1;
  { int i = b * 256 + tid; int k = i >> 6, m = i & 63; WT2[m * 256 + k] = f2b(W2[i]); }
}

// ---------- layers 1/2 GEMM: A bf16 from global, B = WT ----------
template <int H>
__global__ __launch_bounds__(256) void gemm_att_kernel(
    const ushort_t* __restrict__ Ab,   // [N,256] bf16
    const ushort_t* __restrict__ WT,   // [H*64, 256] bf16
    const float* __restrict__ atts, const float* __restrict__ attd,
    ushort_t* __restrict__ hb, float* __restrict__ a_s, float* __restrict__ a_d) {
  const int K = 256, M = H * 64;
  int tid = threadIdx.x, wave = tid >> 6, lane = tid & 63;
  int quad = lane >> 4, l16 = lane & 15;
  int n0 = blockIdx.x * 64, head = blockIdx.y, m0 = head * 64;
  int row = n0 + wave * 16 + l16;
  int rowc = row < NNODES ? row : NNODES - 1;
  f32x4 acc[4];
#pragma unroll
  for (int t = 0; t < 4; ++t) acc[t] = (f32x4){0.f, 0.f, 0.f, 0.f};
  const ushort_t* Ap = Ab + (size_t)rowc * K + quad * 8;
  const ushort_t* Wp = WT + (size_t)(m0 + l16) * K + quad * 8;
  for (int k0 = 0; k0 < K; k0 += 32) {
    bf16x8 af = *(const bf16x8*)(Ap + k0);
#pragma unroll
    for (int t = 0; t < 4; ++t) {
      bf16x8 bf = *(const bf16x8*)(Wp + (size_t)t * 16 * K + k0);
      acc[t] = __builtin_amdgcn_mfma_f32_16x16x32_bf16(af, bf, acc[t], 0, 0, 0);
    }
  }
#pragma unroll
  for (int reg = 0; reg < 4; ++reg) {
    int r = n0 + wave * 16 + quad * 4 + reg;
    float ps = 0.f, pd = 0.f;
#pragma unroll
    for (int t = 0; t < 4; ++t) {
      float v = acc[t][reg];
      int col = m0 + t * 16 + l16;
      ps = fmaf(v, atts[col], ps);
      pd = fmaf(v, attd[col], pd);
      if (r < NNODES) hb[(size_t)r * M + col] = f2b(v);
    }
#pragma unroll
    for (int off = 8; off; off >>= 1) {
      ps += __shfl_xor(ps, off);
      pd += __shfl_xor(pd, off);
    }
    if (l16 == 0 && r < NNODES) {
      a_s[r * H + head] = ps;
      a_d[r * H + head] = pd;
    }
  }
}

// ---------- gather cores ----------
__device__ __forceinline__ void gather8_full(const char* base, const float* alds,
                                             const int* olds, int esub, float acc[8]) {
#pragma unroll
  for (int it = 0; it < 8; ++it) {
    int e = it * 8 + esub;
    float a = alds[e];
    int o = olds[e];
    uint4 q = *(const uint4*)(base + o);
    acc[0] = fmaf(a, blo(q.x), acc[0]); acc[1] = fmaf(a, bhi(q.x), acc[1]);
    acc[2] = fmaf(a, blo(q.y), acc[2]); acc[3] = fmaf(a, bhi(q.y), acc[3]);
    acc[4] = fmaf(a, blo(q.z), acc[4]); acc[5] = fmaf(a, bhi(q.z), acc[5]);
    acc[6] = fmaf(a, blo(q.w), acc[6]); acc[7] = fmaf(a, bhi(q.w), acc[7]);
  }
}

__device__ __forceinline__ void gather8(const char* base, const float* alds, const int* olds,
                                        int cnt, int esub, float acc[8]) {
  int iters = (cnt + 7) >> 3;
  for (int it = 0; it < iters; ++it) {
    int e = it * 8 + esub;
    float a = alds[e];
    int o = olds[e];
    uint4 q = *(const uint4*)(base + o);
    acc[0] = fmaf(a, blo(q.x), acc[0]); acc[1] = fmaf(a, bhi(q.x), acc[1]);
    acc[2] = fmaf(a, blo(q.y), acc[2]); acc[3] = fmaf(a, bhi(q.y), acc[3]);
    acc[4] = fmaf(a, blo(q.z), acc[4]); acc[5] = fmaf(a, bhi(q.z), acc[5]);
    acc[6] = fmaf(a, blo(q.w), acc[6]); acc[7] = fmaf(a, bhi(q.w), acc[7]);
  }
}

// ---------- aggregation layers 0/1 (H=4): softmax + gather + bias+ELU+BN ----------
__global__ __launch_bounds__(256) void aggregate_kernel(
    const ushort_t* __restrict__ hb16, const float* __restrict__ a_s,
    const float* __restrict__ a_d,
    const int* __restrict__ cursor, const int* __restrict__ srcsPad,
    const float* __restrict__ bias, const float* __restrict__ gam, const float* __restrict__ bet,
    const float* __restrict__ rmean, const float* __restrict__ rvar,
    ushort_t* __restrict__ xb16) {
  __shared__ float s_alpha[4][64];
  __shared__ int s_off[4][64];
  int n = blockIdx.x;
  int hh = threadIdx.x >> 6;  // wave = head
  int lane = threadIdx.x & 63;
  int esub = lane >> 3, csub = lane & 7;
  float* alds = s_alpha[hh];
  int* olds = s_off[hh];
  int degi = cursor[n];
  int dtot = degi + 1;  // + self loop
  float adn = a_d[n * 4 + hh];
  const char* base = (const char*)hb16 + hh * 128 + csub * 16;
  float acc[8];
#pragma unroll
  for (int i = 0; i < 8; ++i) acc[i] = 0.f;

  if (dtot <= 64) {
    int s = (lane < degi) ? srcsPad[n * CAP + lane] : n;  // lane==degi -> self; > -> alpha 0
    float l = (lane < dtot) ? lrelu(a_s[s * 4 + hh] + adn) : -1e30f;
    float mx = l;
#pragma unroll
    for (int off = 32; off; off >>= 1) mx = fmaxf(mx, __shfl_xor(mx, off));
    float e = (lane < dtot) ? __expf(l - mx) : 0.f;
    float sum = e;
#pragma unroll
    for (int off = 32; off; off >>= 1) sum += __shfl_xor(sum, off);
    alds[lane] = e / (sum + 1e-16f);
    olds[lane] = s * 512;
    gather8_full(base, alds, olds, esub, acc);
  } else {
    float mx = -1e30f;
    for (int j = lane; j < dtot; j += 64) {
      int s = (j < degi) ? srcsPad[n * CAP + j] : n;
      mx = fmaxf(mx, lrelu(a_s[s * 4 + hh] + adn));
    }
#pragma unroll
    for (int off = 32; off; off >>= 1) mx = fmaxf(mx, __shfl_xor(mx, off));
    float sum = 0.f;
    for (int j = lane; j < dtot; j += 64) {
      int s = (j < degi) ? srcsPad[n * CAP + j] : n;
      sum += __expf(lrelu(a_s[s * 4 + hh] + adn) - mx);
    }
#pragma unroll
    for (int off = 32; off; off >>= 1) sum += __shfl_xor(sum, off);
    float inv = 1.0f / (sum + 1e-16f);
    for (int j0 = 0; j0 < dtot; j0 += 64) {
      int cnt = min(64, dtot - j0);
      int j = j0 + lane;
      int s = (j < degi) ? srcsPad[n * CAP + j] : n;
      alds[lane] = (lane < cnt) ? __expf(lrelu(a_s[s * 4 + hh] + adn) - mx) * inv : 0.f;
      olds[lane] = s * 512;
      gather8(base, alds, olds, cnt, esub, acc);
    }
  }

#pragma unroll
  for (int i = 0; i < 8; ++i) {
    acc[i] += __shfl_xor(acc[i], 8);
    acc[i] += __shfl_xor(acc[i], 16);
    acc[i] += __shfl_xor(acc[i], 32);
  }
  if (esub == 0) {
    int col0 = hh * 64 + csub * 8;
    float4 bi0 = *(const float4*)&bias[col0],  bi1 = *(const float4*)&bias[col0 + 4];
    float4 gm0 = *(const float4*)&gam[col0],   gm1 = *(const float4*)&gam[col0 + 4];
    float4 bt0 = *(const float4*)&bet[col0],   bt1 = *(const float4*)&bet[col0 + 4];
    float4 rm0 = *(const float4*)&rmean[col0], rm1 = *(const float4*)&rmean[col0 + 4];
    float4 rv0 = *(const float4*)&rvar[col0],  rv1 = *(const float4*)&rvar[col0 + 4];
    float bi[8] = {bi0.x, bi0.y, bi0.z, bi0.w, bi1.x, bi1.y, bi1.z, bi1.w};
    float gm[8] = {gm0.x, gm0.y, gm0.z, gm0.w, gm1.x, gm1.y, gm1.z, gm1.w};
    float bt[8] = {bt0.x, bt0.y, bt0.z, bt0.w, bt1.x, bt1.y, bt1.z, bt1.w};
    float rm[8] = {rm0.x, rm0.y, rm0.z, rm0.w, rm1.x, rm1.y, rm1.z, rm1.w};
    float rv[8] = {rv0.x, rv0.y, rv0.z, rv0.w, rv1.x, rv1.y, rv1.z, rv1.w};
    unsigned pk[4];
#pragma unroll
    for (int i = 0; i < 4; ++i) {
      float v0 = acc[2 * i] + bi[2 * i], v1 = acc[2 * i + 1] + bi[2 * i + 1];
      v0 = v0 > 0.f ? v0 : (__expf(v0) - 1.f);
      v1 = v1 > 0.f ? v1 : (__expf(v1) - 1.f);
      v0 = fmaf(gm[2 * i] * (v0 - rm[2 * i]), rsqrtf(rv[2 * i] + 1e-5f), bt[2 * i]);
      v1 = fmaf(gm[2 * i + 1] * (v1 - rm[2 * i + 1]), rsqrtf(rv[2 * i + 1] + 1e-5f), bt[2 * i + 1]);
      pk[i] = (unsigned)f2b(v0) | ((unsigned)f2b(v1) << 16);
    }
    *(uint4*)((char*)xb16 + (size_t)n * 512 + col0 * 2) = make_uint4(pk[0], pk[1], pk[2], pk[3]);
  }
}

// ---------- aggregation layer 2 (H=1) + bias + log_softmax ----------
__global__ __launch_bounds__(256) void aggregate2_kernel(
    const ushort_t* __restrict__ hb16, const float* __restrict__ a_s,
    const float* __restrict__ a_d,
    const int* __restrict__ cursor, const int* __restrict__ srcsPad,
    const float* __restrict__ bias, float* __restrict__ out) {
  __shared__ float s_alpha[4][64];
  __shared__ int s_off[4][64];
  int wave = threadIdx.x >> 6;
  int n = blockIdx.x * 4 + wave;
  int lane = threadIdx.x & 63;
  int esub = lane >> 3, csub = lane & 7;
  if (n >= NNODES) return;
  float* alds = s_alpha[wave];
  int* olds = s_off[wave];
  int degi = cursor[n];
  int dtot = degi + 1;
  float adn = a_d[n];
  const char* base = (const char*)hb16 + csub * 16;
  float acc[8];
#pragma unroll
  for (int i = 0; i < 8; ++i) acc[i] = 0.f;

  if (dtot <= 64) {
    int s = (lane < degi) ? srcsPad[n * CAP + lane] : n;
    float l = (lane < dtot) ? lrelu(a_s[s] + adn) : -1e30f;
    float mx = l;
#pragma unroll
    for (int off = 32; off; off >>= 1) mx = fmaxf(mx, __shfl_xor(mx, off));
    float e = (lane < dtot) ? __expf(l - mx) : 0.f;
    float sum = e;
#pragma unroll
    for (int off = 32; off; off >>= 1) sum += __shfl_xor(sum, off);
    alds[lane] = e / (sum + 1e-16f);
    olds[lane] = s * 128;
    gather8_full(base, alds, olds, esub, acc);
  } else {
    float mx = -1e30f;
    for (int j = lane; j < dtot; j += 64) {
      int s = (j < degi) ? srcsPad[n * CAP + j] : n;
      mx = fmaxf(mx, lrelu(a_s[s] + adn));
    }
#pragma unroll
    for (int off = 32; off; off >>= 1) mx = fmaxf(mx, __shfl_xor(mx, off));
    float sum = 0.f;
    for (int j = lane; j < dtot; j += 64) {
      int s = (j < degi) ? srcsPad[n * CAP + j] : n;
      sum += __expf(lrelu(a_s[s] + adn) - mx);
    }
#pragma unroll
    for (int off = 32; off; off >>= 1) sum += __shfl_xor(sum, off);
    float inv = 1.0f / (sum + 1e-16f);
    for (int j0 = 0; j0 < dtot; j0 += 64) {
      int cnt = min(64, dtot - j0);
      int j = j0 + lane;
      int s = (j < degi) ? srcsPad[n * CAP + j] : n;
      alds[lane] = (lane < cnt) ? __expf(lrelu(a_s[s] + adn) - mx) * inv : 0.f;
      olds[lane] = s * 128;
      gather8(base, alds, olds, cnt, esub, acc);
    }
  }

#pragma unroll
  for (int i = 0; i < 8; ++i) {
    acc[i] += __shfl_xor(acc[i], 8);
    acc[i] += __shfl_xor(acc[i], 16);
    acc[i] += __shfl_xor(acc[i], 32);
  }
  int col0 = csub * 8;
  float4 bi0 = *(const float4*)&bias[col0], bi1 = *(const float4*)&bias[col0 + 4];
  float v[8] = {acc[0] + bi0.x, acc[1] + bi0.y, acc[2] + bi0.z, acc[3] + bi0.w,
                acc[4] + bi1.x, acc[5] + bi1.y, acc[6] + bi1.z, acc[7] + bi1.w};
  float mx = v[0];
#pragma unroll
  for (int i = 1; i < 8; ++i) mx = fmaxf(mx, v[i]);
#pragma unroll
  for (int off = 4; off; off >>= 1) mx = fmaxf(mx, __shfl_xor(mx, off));
  float ex = 0.f;
#pragma unroll
  for (int i = 0; i < 8; ++i) ex += __expf(v[i] - mx);
#pragma unroll
  for (int off = 4; off; off >>= 1) ex += __shfl_xor(ex, off);
  float lse = mx + logf(ex);
  if (esub == 0) {
    float4 o0 = make_float4(v[0] - lse, v[1] - lse, v[2] - lse, v[3] - lse);
    float4 o1 = make_float4(v[4] - lse, v[5] - lse, v[6] - lse, v[7] - lse);
    *(float4*)&out[(size_t)n * 64 + col0] = o0;
    *(float4*)&out[(size_t)n * 64 + col0 + 4] = o1;
  }
}

// ---------- host ----------
extern "C" void kernel_launch(void* const* d_in, const int* in_sizes, int n_in,
                              void* d_out, int out_size, void* d_ws, size_t ws_size,
                              hipStream_t stream) {
  const float* x = (const float*)d_in[0];
  const int* ei = (const int*)d_in[1];
  const float* W0 = (const float*)d_in[2];
  const float* as0 = (const float*)d_in[3];
  const float* ad0 = (const float*)d_in[4];
  const float* b0 = (const float*)d_in[5];
  const float* g0p = (const float*)d_in[6];
  const float* be0 = (const float*)d_in[7];
  const float* m0p = (const float*)d_in[8];
  const float* v0p = (const float*)d_in[9];
  const float* W1 = (const float*)d_in[10];
  const float* as1 = (const float*)d_in[11];
  const float* ad1 = (const float*)d_in[12];
  const float* b1 = (const float*)d_in[13];
  const float* g1p = (const float*)d_in[14];
  const float* be1 = (const float*)d_in[15];
  const float* m1p = (const float*)d_in[16];
  const float* v1p = (const float*)d_in[17];
  const float* W2 = (const float*)d_in[18];
  const float* as2 = (const float*)d_in[19];
  const float* ad2 = (const float*)d_in[20];
  const float* b2 = (const float*)d_in[21];
  float* out = (float*)d_out;

  char* w = (char*)d_ws;
  auto alloc = [&](size_t bytes) {
    void* r = (void*)w;
    w += (bytes + 255) & ~(size_t)255;
    return r;
  };
  ushort_t* hb = (ushort_t*)alloc((size_t)NNODES * 256 * 2);   // per-layer h (reused)
  ushort_t* xb = (ushort_t*)alloc((size_t)NNODES * 256 * 2);   // aggregate output (reused)
  ushort_t* WT0 = (ushort_t*)alloc((size_t)256 * 128 * 2);
  ushort_t* WT1 = (ushort_t*)alloc((size_t)256 * 256 * 2);
  ushort_t* WT2 = (ushort_t*)alloc((size_t)64 * 256 * 2);
  float* a_s = (float*)alloc((size_t)NNODES * 4 * 4);
  float* a_d = (float*)alloc((size_t)NNODES * 4 * 4);
  int* cursor = (int*)alloc((size_t)NNODES * 4);
  int* srcsPad = (int*)alloc((size_t)NNODES * CAP * 4);

  // 1. prep: W0 transpose + cursor zeroing (memset dispatch eliminated)
  prep_kernel<<<BW0 + BZ, 256, 0, stream>>>(W0, WT0, cursor);
  // 2. layer-0 GEMM + att, fused with bucket scatter and W1/W2 transposes
  gemm0_scatter_kernel<<<NBLK * 4 + BSC + BW1 + BW2, 256, 0, stream>>>(
      x, WT0, as0, ad0, hb, a_s, a_d, ei, cursor, srcsPad, W1, W2, WT1, WT2);
  // 3. layer-0 aggregate
  aggregate_kernel<<<NNODES, 256, 0, stream>>>(hb, a_s, a_d, cursor, srcsPad,
                                               b0, g0p, be0, m0p, v0p, xb);
  // 4-5. layer 1
  gemm_att_kernel<4><<<dim3(NBLK, 4), 256, 0, stream>>>(xb, WT1, as1, ad1, hb, a_s, a_d);
  aggregate_kernel<<<NNODES, 256, 0, stream>>>(hb, a_s, a_d, cursor, srcsPad,
                                               b1, g1p, be1, m1p, v1p, xb);
  // 6-7. layer 2
  gemm_att_kernel<1><<<dim3(NBLK, 1), 256, 0, stream>>>(xb, WT2, as2, ad2, hb, a_s, a_d);
  aggregate2_kernel<<<(NNODES + 3) / 4, 256, 0, stream>>>(hb, a_s, a_d, cursor, srcsPad,
                                                          b2, out);
}